// Round 15
// baseline (161.337 us; speedup 1.0000x reference)
//
#include <hip/hip_runtime.h>
#include <hip/hip_bf16.h>
#include <cstdint>

#define T_TOK 2048
#define HID   2048
#define NEXP  64
#define TOPK  6
#define NLOC  8
#define ITR   1408
#define ITR2  2816
#define NSLOT (T_TOK * TOPK)
#define KC1   1024  // gemm1 k-chunk (HID/2)
#define KC2   704   // gemm2 k-chunk (ITR/2)
#define NS1   16    // KC1/64
#define NS2   11    // KC2/64

// workspace layout (bytes)
#define OFF_CNT   0
#define OFF_CNT2  32
#define OFF_TOPID 4096
#define OFF_TOPW  (OFF_TOPID + T_TOK * TOPK * 4)
#define OFF_TOK   (OFF_TOPW  + T_TOK * TOPK * 4)
#define OFF_WOF   (OFF_TOK   + NSLOT * 4)
#define OFF_XBF   (OFF_WOF   + NSLOT * 4)
#define OFF_ABUF  (OFF_XBF   + (size_t)T_TOK * HID * 2)
#define OFF_HP    (OFF_ABUF  + (size_t)NSLOT * ITR * 2)
#define HP_STRIDE ((size_t)NSLOT * ITR2)   // floats per k-copy

typedef __attribute__((ext_vector_type(4))) float f32x4;
typedef __attribute__((ext_vector_type(8))) short s16x8;
typedef __attribute__((ext_vector_type(4))) short s16x4;

__device__ __forceinline__ short f2bf(float f) {
    union { float f; unsigned u; } v; v.f = f;
    unsigned r = v.u + 0x7FFFu + ((v.u >> 16) & 1u);
    return (short)(r >> 16);
}

// one barrier per K-step: drain LDS ops; vmem loads stay in flight (counted reg-dep waits)
#define BAR() do {                                            \
    asm volatile("s_waitcnt lgkmcnt(0)" ::: "memory");        \
    __builtin_amdgcn_s_barrier();                             \
    asm volatile("" ::: "memory");                            \
} while (0)

// ---------------- prep: zero d_out + counters, cvt x -> bf16 ----------------
__global__ __launch_bounds__(256) void k_prep(const float* __restrict__ x,
                                              short* __restrict__ xbf,
                                              float* __restrict__ out,
                                              int* __restrict__ cnt)
{
    const int r = blockIdx.x;
    const int c = threadIdx.x * 8;
    const float4 a = *(const float4*)&x[(size_t)r * HID + c];
    const float4 b = *(const float4*)&x[(size_t)r * HID + c + 4];
    s16x8 v = { f2bf(a.x), f2bf(a.y), f2bf(a.z), f2bf(a.w),
                f2bf(b.x), f2bf(b.y), f2bf(b.z), f2bf(b.w) };
    *(s16x8*)&xbf[(size_t)r * HID + c] = v;
    float4 z = {0.f, 0.f, 0.f, 0.f};
    *(float4*)&out[(size_t)r * HID + c] = z;
    *(float4*)&out[(size_t)r * HID + c + 4] = z;
    if (r == 0 && threadIdx.x < 16) cnt[threadIdx.x] = 0;
}

// ---------------- routing: softmax + top-6 (stable tie-break) ----------------
__global__ __launch_bounds__(256) void k_route(
    const float* __restrict__ logits, int* __restrict__ cnt,
    int* __restrict__ top_ids, float* __restrict__ top_w)
{
    const int lane = threadIdx.x & 63;
    const int t = blockIdx.x * 4 + (threadIdx.x >> 6);

    float v = logits[t * NEXP + lane];
    float m = v;
    #pragma unroll
    for (int s = 32; s > 0; s >>= 1) m = fmaxf(m, __shfl_xor(m, s));
    float ev = expf(v - m);
    float ssum = ev;
    #pragma unroll
    for (int s = 32; s > 0; s >>= 1) ssum += __shfl_xor(ssum, s);
    float p = ev / ssum;

    float pv = p;
    int ids[TOPK]; float wsel[TOPK]; float wsum = 0.f;
    #pragma unroll
    for (int i = 0; i < TOPK; ++i) {
        float mx = pv;
        #pragma unroll
        for (int s = 32; s > 0; s >>= 1) mx = fmaxf(mx, __shfl_xor(mx, s));
        unsigned long long b = __ballot(pv == mx);
        int idx = (int)__builtin_ctzll(b);
        float w = __shfl(p, idx);
        ids[i] = idx; wsel[i] = w; wsum += w;
        if (lane == idx) pv = -1.0f;
    }
    if (lane < TOPK) {
        top_ids[t * TOPK + lane] = ids[lane];
        top_w[t * TOPK + lane]  = wsel[lane] / wsum;
    }
    if (lane == 0) {
        #pragma unroll
        for (int i = 0; i < TOPK; ++i)
            if ((ids[i] & 7) == 0) atomicAdd(&cnt[ids[i] >> 3], 1);
    }
}

__global__ __launch_bounds__(256) void k_scatter(
    const int* __restrict__ top_ids, const float* __restrict__ top_w,
    const int* __restrict__ cnt, int* __restrict__ cnt2,
    int* __restrict__ tok_of, float* __restrict__ w_of)
{
    const int t = blockIdx.x * 256 + threadIdx.x;
    int offs[NLOC];
    {
        int s = 0;
        #pragma unroll
        for (int i = 0; i < NLOC; ++i) { offs[i] = s; s += cnt[i]; }
    }
    #pragma unroll
    for (int i = 0; i < TOPK; ++i) {
        int id = top_ids[t * TOPK + i];
        if ((id & 7) == 0) {
            int e = id >> 3;
            int s = offs[e] + atomicAdd(&cnt2[e], 1);
            tok_of[s] = t;
            w_of[s]  = top_w[t * TOPK + i];
        }
    }
}

// ---- GEMM1: BM=256 (weights once), BN=32 pairs, split-K=2, KS=64, 8 waves ----
// A: per-wave-private 4KB strip (no barrier); W: dbuf LDS + 2-DEEP reg prefetch
__global__ __launch_bounds__(512, 4) void k_gemm1(
    const short* __restrict__ xbf, const float* __restrict__ w13,
    const float* __restrict__ w13s, const int* __restrict__ cnt,
    const int* __restrict__ tok_of, float* __restrict__ h_part)
{
    const int b = blockIdx.x;
    const int e = b & 7;
    int t_ = b >> 3;
    const int kc = t_ & 1; t_ >>= 1;
    const int nb = t_ % 44;
    const int m0 = (t_ / 44) * 256;
    int off_e = 0, cntE = 0;
    #pragma unroll
    for (int i = 0; i < NLOC; ++i) { int c = cnt[i]; if (i < e) off_e += c; if (i == e) cntE = c; }
    if (m0 >= cntE) return;
    const int n0p = nb * 32;
    const int base = off_e + m0;
    const int tid = threadIdx.x;
    const int lane = tid & 63;
    const int wm = tid >> 6;          // wave 0..7 owns rows wm*32..+31

    __shared__ __align__(16) short As[8][2048];      // 32 KB: per-wave 32x64 strip
    __shared__ __align__(16) short Ws[2][64 * 64];   // 16 KB: 32 gate + 32 up rows

    // stage token ids through Ws[0] (free until first WRITEW, barriered)
    int* tokp = (int*)&Ws[0][0];
    if (tid < 256) tokp[tid] = tok_of[base + ((m0 + tid < cntE) ? tid : 0)];
    __syncthreads();

    // A stager: 4 loads/thread; load j: row = j*8+(lane>>3), chunk = lane&7 (128B coalesced)
    unsigned ag[4];
    int al[4];
    {
        const int cg = (lane & 7) * 8;
        #pragma unroll
        for (int j = 0; j < 4; ++j) {
            const int row = j * 8 + (lane >> 3);          // wave-local 0..31
            ag[j] = (unsigned)tokp[wm * 32 + row] * HID + (unsigned)(kc * KC1) + cg;
            al[j] = (row * 64 + cg) ^ ((row & 7) << 3);   // row&7 == lane>>3
        }
    }
    __syncthreads();   // done reading tokp; Ws[0] free

    // W stager: 64 rows (32 gate + 32 up) x 64 fp32 per step; 8 floats/thread
    const int wrow = tid >> 3;
    const int wcol = (tid & 7) * 8;
    const float* wptr = w13 + ((size_t)e * ITR2 +
        (wrow < 32 ? n0p + wrow : ITR + n0p + (wrow - 32))) * HID + kc * KC1 + wcol;
    const int woff  = (wrow * 64 + wcol) ^ ((wrow & 7) << 3);
    const int sbase = (e * 22 + (wrow < 32 ? 0 : 11) + (n0p >> 7)) * 16 + kc * 8;

    s16x8 ra[4];
    float4 rw0A, rw1A, rw0B, rw1B;   // 2-deep W slots (by step parity)
    float svA, svB;
    f32x4 acc[2][2][2] = {};   // [gate/up][nf][mf]

#define LOADA(kk) do { const int k0 = min((kk), NS1 - 1) * 64;                 \
    _Pragma("unroll")                                                          \
    for (int j = 0; j < 4; ++j) ra[j] = *(const s16x8*)(xbf + ag[j] + k0);     \
} while (0)

#define WRITEA() do { _Pragma("unroll")                                        \
    for (int j = 0; j < 4; ++j) *(s16x8*)&As[wm][al[j]] = ra[j]; } while (0)

#define LOADW(kk, S) do { const int kq = min((kk), NS1 - 1);                   \
    rw0##S = *(const float4*)(wptr + kq * 64);                                 \
    rw1##S = *(const float4*)(wptr + kq * 64 + 4);                             \
    sv##S  = w13s[sbase + (kq >> 1)]; } while (0)

#define WRITEW(bf, S) do {                                                     \
    s16x8 v = { f2bf(rw0##S.x * sv##S), f2bf(rw0##S.y * sv##S),                \
                f2bf(rw0##S.z * sv##S), f2bf(rw0##S.w * sv##S),                \
                f2bf(rw1##S.x * sv##S), f2bf(rw1##S.y * sv##S),                \
                f2bf(rw1##S.z * sv##S), f2bf(rw1##S.w * sv##S) };              \
    *(s16x8*)&Ws[bf][woff] = v; } while (0)

#define COMP(bf) do { _Pragma("unroll")                                        \
    for (int ks = 0; ks < 2; ++ks) {                                           \
        const int co = ks * 32 + (lane >> 4) * 8;                              \
        s16x8 af[2];                                                           \
        _Pragma("unroll")                                                      \
        for (int mf = 0; mf < 2; ++mf) {                                       \
            const int row = mf * 16 + (lane & 15);                             \
            af[mf] = *(const s16x8*)&As[wm][(row * 64 + co) ^ ((row & 7) << 3)]; \
        }                                                                      \
        _Pragma("unroll")                                                      \
        for (int t = 0; t < 2; ++t)                                            \
        _Pragma("unroll")                                                      \
        for (int nf = 0; nf < 2; ++nf) {                                       \
            const int brow = t * 32 + nf * 16 + (lane & 15);                   \
            s16x8 bv = *(const s16x8*)&Ws[bf][(brow * 64 + co) ^ ((brow & 7) << 3)]; \
            _Pragma("unroll")                                                  \
            for (int mf = 0; mf < 2; ++mf)                                     \
                acc[t][nf][mf] = __builtin_amdgcn_mfma_f32_16x16x32_bf16(af[mf], bv, acc[t][nf][mf], 0, 0, 0); \
        } } } while (0)

    // prologue: W prefetched 2 slots deep (W0 staged, W1 in B, W2 in A)
    LOADA(0); LOADW(0, A);
    WRITEA(); WRITEW(0, A);
    LOADA(1); LOADW(1, B);
    LOADW(2, A);
    BAR();
    // steady state (NS1 even): each half-iter = one K-step, one barrier
    for (int k = 0; k < NS1; k += 2) {
        COMP(0);
        WRITEA(); LOADA(k + 2);
        WRITEW(1, B); LOADW(k + 3, B);   // W(k+1) staged; W(k+3) in flight 2 iters
        BAR();
        COMP(1);
        WRITEA(); LOADA(k + 3);
        WRITEW(0, A); LOADW(k + 4, A);
        BAR();
    }

    // epilogue: fp32 partials (disjoint per kc)
    float* hp = h_part + (size_t)kc * HP_STRIDE;
    #pragma unroll
    for (int t = 0; t < 2; ++t)
    #pragma unroll
    for (int nf = 0; nf < 2; ++nf) {
        const int col = t * ITR + n0p + nf * 16 + (lane & 15);
        #pragma unroll
        for (int mf = 0; mf < 2; ++mf)
        #pragma unroll
        for (int j = 0; j < 4; ++j) {
            const int row = wm * 32 + mf * 16 + (lane >> 4) * 4 + j;
            if (m0 + row < cntE)
                hp[(size_t)(base + row) * ITR2 + col] = acc[t][nf][mf][j];
        }
    }
#undef LOADA
#undef WRITEA
#undef LOADW
#undef WRITEW
#undef COMP
}

// ---- silu reduce: a = silu(hg0+hg1) * (hu0+hu1) -> a_buf bf16 ----
__global__ __launch_bounds__(256) void k_silu(
    const float* __restrict__ h_part, const int* __restrict__ cnt,
    short* __restrict__ a_buf)
{
    int total = 0;
    #pragma unroll
    for (int i = 0; i < NLOC; ++i) total += cnt[i];
    const int s = blockIdx.x;
    if (s >= total) return;
    const float* h0 = h_part + (size_t)s * ITR2;
    const float* h1 = h0 + HP_STRIDE;
    short* ao = a_buf + (size_t)s * ITR;
    for (int c = threadIdx.x; c < ITR; c += 256) {
        const float g = h0[c] + h1[c];
        const float u = h0[ITR + c] + h1[ITR + c];
        ao[c] = f2bf((g / (1.f + __expf(-g))) * u);
    }
}

// ---- GEMM2: BM=256, BN=32 out-cols, split-K=2, KS=64, 8 waves, 2-deep W ----
__global__ __launch_bounds__(512, 4) void k_gemm2(
    const short* __restrict__ a_buf, const float* __restrict__ w2,
    const float* __restrict__ w2s, const int* __restrict__ cnt,
    const int* __restrict__ tok_of, const float* __restrict__ w_of,
    float* __restrict__ out)
{
    const int b = blockIdx.x;
    const int e = b & 7;
    int t_ = b >> 3;
    const int kc = t_ & 1; t_ >>= 1;
    const int nb = t_ % 64;
    const int m0 = (t_ / 64) * 256;
    int off_e = 0, cntE = 0;
    #pragma unroll
    for (int i = 0; i < NLOC; ++i) { int c = cnt[i]; if (i < e) off_e += c; if (i == e) cntE = c; }
    if (m0 >= cntE) return;
    const int n0 = nb * 32;
    const int base = off_e + m0;
    const int tid = threadIdx.x;
    const int lane = tid & 63;
    const int wm = tid >> 6;

    __shared__ __align__(16) short As[8][2048];      // 32 KB
    __shared__ __align__(16) short Ws[2][32 * 64];   // 8 KB

    unsigned ag[4];
    int al[4];
    {
        const int cg = (lane & 7) * 8;
        #pragma unroll
        for (int j = 0; j < 4; ++j) {
            const int row = j * 8 + (lane >> 3);
            int slot = base + wm * 32 + row;
            if (slot > NSLOT - 1) slot = NSLOT - 1;
            ag[j] = (unsigned)slot * ITR + (unsigned)(kc * KC2) + cg;
            al[j] = (row * 64 + cg) ^ ((row & 7) << 3);
        }
    }
    // W stager: 32 rows x 64 fp32 per step; 4 floats/thread
    const int wrow = tid >> 4;
    const int wcol = (tid & 15) * 4;
    const float* wptr = w2 + ((size_t)e * HID + n0 + wrow) * ITR + kc * KC2 + wcol;
    const int woff  = (wrow * 64 + wcol) ^ ((wrow & 7) << 3);
    const int sbase = (e * 16 + (n0 >> 7)) * 11;
    const int skoff = kc * KC2;

    s16x8 ra[4];
    float4 rw0A, rw0B;
    float svA, svB;
    f32x4 acc[2][2] = {};   // [nf][mf]

#define LOADA(kk) do { const int k0 = min((kk), NS2 - 1) * 64;                 \
    _Pragma("unroll")                                                          \
    for (int j = 0; j < 4; ++j) ra[j] = *(const s16x8*)(a_buf + ag[j] + k0);   \
} while (0)

#define WRITEA() do { _Pragma("unroll")                                        \
    for (int j = 0; j < 4; ++j) *(s16x8*)&As[wm][al[j]] = ra[j]; } while (0)

#define LOADW(kk, S) do { const int kq = min((kk), NS2 - 1);                   \
    rw0##S = *(const float4*)(wptr + kq * 64);                                 \
    sv##S  = w2s[sbase + ((skoff + kq * 64) >> 7)]; } while (0)

#define WRITEW(bf, S) do {                                                     \
    s16x4 v = { f2bf(rw0##S.x * sv##S), f2bf(rw0##S.y * sv##S),                \
                f2bf(rw0##S.z * sv##S), f2bf(rw0##S.w * sv##S) };              \
    *(s16x4*)&Ws[bf][woff] = v; } while (0)

#define COMP(bf) do { _Pragma("unroll")                                        \
    for (int ks = 0; ks < 2; ++ks) {                                           \
        const int co = ks * 32 + (lane >> 4) * 8;                              \
        s16x8 af[2];                                                           \
        _Pragma("unroll")                                                      \
        for (int mf = 0; mf < 2; ++mf) {                                       \
            const int row = mf * 16 + (lane & 15);                             \
            af[mf] = *(const s16x8*)&As[wm][(row * 64 + co) ^ ((row & 7) << 3)]; \
        }                                                                      \
        _Pragma("unroll")                                                      \
        for (int nf = 0; nf < 2; ++nf) {                                       \
            const int brow = nf * 16 + (lane & 15);                            \
            s16x8 bv = *(const s16x8*)&Ws[bf][(brow * 64 + co) ^ ((brow & 7) << 3)]; \
            _Pragma("unroll")                                                  \
            for (int mf = 0; mf < 2; ++mf)                                     \
                acc[nf][mf] = __builtin_amdgcn_mfma_f32_16x16x32_bf16(af[mf], bv, acc[nf][mf], 0, 0, 0); \
        } } } while (0)

    LOADA(0); LOADW(0, A);
    WRITEA(); WRITEW(0, A);
    LOADA(1); LOADW(1, B);
    LOADW(2, A);
    BAR();
    // NS2 = 11 (odd): double-step loop over steps 0..9, peeled tail for step 10
    for (int k = 0; k + 2 < NS2; k += 2) {
        COMP(0);
        WRITEA(); LOADA(k + 2);
        WRITEW(1, B); LOADW(k + 3, B);
        BAR();
        COMP(1);
        WRITEA(); LOADA(k + 3);
        WRITEW(0, A); LOADW(k + 4, A);
        BAR();
    }
    COMP(0);   // step 10: A(10) staged at k=8 2nd half; W(10) staged+BAR'd at k=8 2nd half

    #pragma unroll
    for (int mf = 0; mf < 2; ++mf)
    #pragma unroll
    for (int j = 0; j < 4; ++j) {
        const int row = wm * 32 + mf * 16 + (lane >> 4) * 4 + j;
        if (m0 + row < cntE) {
            const int   t = tok_of[base + row];
            const float w = w_of[base + row];
            #pragma unroll
            for (int nf = 0; nf < 2; ++nf) {
                const int col = n0 + nf * 16 + (lane & 15);
                atomicAdd(&out[(size_t)t * HID + col], acc[nf][mf][j] * w);
            }
        }
    }
#undef LOADA
#undef WRITEA
#undef LOADW
#undef WRITEW
#undef COMP
}

extern "C" void kernel_launch(void* const* d_in, const int* in_sizes, int n_in,
                              void* d_out, int out_size, void* d_ws, size_t ws_size,
                              hipStream_t stream)
{
    const float* x      = (const float*)d_in[0];
    const float* logits = (const float*)d_in[1];
    const float* w13    = (const float*)d_in[2];
    const float* w13s   = (const float*)d_in[3];
    const float* w2     = (const float*)d_in[4];
    const float* w2s    = (const float*)d_in[5];
    float* out = (float*)d_out;
    char*  ws  = (char*)d_ws;

    int*   cnt     = (int*)(ws + OFF_CNT);
    int*   cnt2    = (int*)(ws + OFF_CNT2);
    int*   top_ids = (int*)(ws + OFF_TOPID);
    float* top_w   = (float*)(ws + OFF_TOPW);
    int*   tok_of  = (int*)(ws + OFF_TOK);
    float* w_of    = (float*)(ws + OFF_WOF);
    short* xbf     = (short*)(ws + OFF_XBF);
    short* a_buf   = (short*)(ws + OFF_ABUF);
    float* h_part  = (float*)(ws + OFF_HP);

    k_prep   <<<T_TOK,       256, 0, stream>>>(x, xbf, out, cnt);
    k_route  <<<T_TOK / 4,   256, 0, stream>>>(logits, cnt, top_ids, top_w);
    k_scatter<<<T_TOK / 256, 256, 0, stream>>>(top_ids, top_w, cnt, cnt2, tok_of, w_of);
    // flat ids: e in low 3 bits (XCD round-robin), kc next, n, m slowest (live-first)
    k_gemm1  <<<44 * 2 * 2 * 8, 512, 0, stream>>>(xbf, w13, w13s, cnt, tok_of, h_part);
    k_silu   <<<NSLOT,       256, 0, stream>>>(h_part, cnt, a_buf);
    k_gemm2  <<<64 * 2 * 2 * 8, 512, 0, stream>>>(a_buf, w2, w2s, cnt, tok_of, w_of, out);
}